// Round 1
// baseline (1281.448 us; speedup 1.0000x reference)
//
#include <hip/hip_runtime.h>
#include <hip/hip_bf16.h>

#define BB 8
#define CC 128
#define NN 4096
#define HH 4
#define FF 128
#define KK 16
#define HF 512   // H*F

__device__ __forceinline__ float bf2f(unsigned int u) {
  return __uint_as_float(u << 16);
}

__device__ __forceinline__ unsigned short f2bf(float f) {
  unsigned int u = __float_as_uint(f);
  unsigned int lsb = (u >> 16) & 1u;
  u += 0x7fffu + lsb;                 // RTNE
  return (unsigned short)(u >> 16);
}

// ---------------------------------------------------------------------------
// sq[b][n] = sum_c x[b][c][n]^2
__global__ void k_sq(const float* __restrict__ x, float* __restrict__ sq) {
  int idx = blockIdx.x * 256 + threadIdx.x;        // b*N + n
  int b = idx >> 12, n = idx & (NN - 1);
  const float* xb = x + (size_t)b * CC * NN + n;
  float s = 0.f;
#pragma unroll 8
  for (int c = 0; c < CC; ++c) {
    float v = xb[(size_t)c * NN];
    s += v * v;
  }
  sq[idx] = s;
}

// ---------------------------------------------------------------------------
// Fused per-batch Gram + top-16 (smallest  sq[col] - 2*dot  per row).
// Block: 64 rows of one batch; loops 64 column-chunks of 64.
__launch_bounds__(256)
__global__ void k_knn(const float* __restrict__ x, const float* __restrict__ sq,
                      int* __restrict__ nbr) {
  __shared__ float As[CC][64];   // [c][row]  32 KB (full K)
  __shared__ float Bs[64][64];   // [c-half][col] 16 KB
  __shared__ float Dt[64][65];   // distance tile (pad 65: conflict-free row scan)
  __shared__ float scol[64];

  int b = blockIdx.x >> 6, rb = blockIdx.x & 63;
  const float* xb = x + (size_t)b * CC * NN;
  int tid = threadIdx.x;
  int tx = tid & 15, ty = tid >> 4;

  for (int i = tid; i < CC * 64; i += 256) {
    int c = i >> 6, r = i & 63;
    As[c][r] = xb[(size_t)c * NN + rb * 64 + r];
  }

  float bd[KK]; int bi[KK];
#pragma unroll
  for (int i = 0; i < KK; ++i) { bd[i] = 3.4e38f; bi[i] = 0; }
  float worst = 3.4e38f; int wslot = 0;

  for (int cb = 0; cb < 64; ++cb) {
    if (tid < 64) scol[tid] = sq[b * NN + cb * 64 + tid];
    // stage B half 0 (c = 0..63)
    for (int i = tid; i < 64 * 64; i += 256) {
      int c = i >> 6, col = i & 63;
      Bs[c][col] = xb[(size_t)c * NN + cb * 64 + col];
    }
    __syncthreads();

    float acc[4][4];
#pragma unroll
    for (int i = 0; i < 4; ++i)
#pragma unroll
      for (int j = 0; j < 4; ++j) acc[i][j] = 0.f;

#pragma unroll 8
    for (int c = 0; c < 64; ++c) {
      float4 a4 = *(const float4*)&As[c][ty * 4];
      float4 b4 = *(const float4*)&Bs[c][tx * 4];
      float av[4] = {a4.x, a4.y, a4.z, a4.w};
      float bv[4] = {b4.x, b4.y, b4.z, b4.w};
#pragma unroll
      for (int i = 0; i < 4; ++i)
#pragma unroll
        for (int j = 0; j < 4; ++j) acc[i][j] += av[i] * bv[j];
    }
    __syncthreads();   // done reading Bs half 0

    // stage B half 1 (c = 64..127)
    for (int i = tid; i < 64 * 64; i += 256) {
      int c = i >> 6, col = i & 63;
      Bs[c][col] = xb[(size_t)(64 + c) * NN + cb * 64 + col];
    }
    __syncthreads();

#pragma unroll 8
    for (int c = 0; c < 64; ++c) {
      float4 a4 = *(const float4*)&As[64 + c][ty * 4];
      float4 b4 = *(const float4*)&Bs[c][tx * 4];
      float av[4] = {a4.x, a4.y, a4.z, a4.w};
      float bv[4] = {b4.x, b4.y, b4.z, b4.w};
#pragma unroll
      for (int i = 0; i < 4; ++i)
#pragma unroll
        for (int j = 0; j < 4; ++j) acc[i][j] += av[i] * bv[j];
    }

    // shifted distance: s = sq[col] - 2*dot  (same per-row ordering as ref)
#pragma unroll
    for (int i = 0; i < 4; ++i)
#pragma unroll
      for (int j = 0; j < 4; ++j)
        Dt[ty * 4 + i][tx * 4 + j] = scol[tx * 4 + j] - 2.f * acc[i][j];
    __syncthreads();

    // wave-0 serial top-k scan; insertion is rare after warm-up
    if (tid < 64) {
#pragma unroll 4
      for (int col = 0; col < 64; ++col) {
        float d = Dt[tid][col];
        if (d < worst) {
          int idx = cb * 64 + col;
#pragma unroll
          for (int i = 0; i < KK; ++i)
            if (i == wslot) { bd[i] = d; bi[i] = idx; }
          worst = bd[0]; wslot = 0;
#pragma unroll
          for (int i = 1; i < KK; ++i)
            if (bd[i] > worst) { worst = bd[i]; wslot = i; }
        }
      }
    }
    __syncthreads();
  }

  if (tid < 64) {
    int row = rb * 64 + tid;
    int* o = nbr + ((size_t)b * NN + row) * KK;
#pragma unroll
    for (int i = 0; i < KK; ++i) o[i] = bi[i];
  }
}

// ---------------------------------------------------------------------------
// h[b][n][hf] = sum_c x[b][c][n] * W[c][hf], stored bf16
__launch_bounds__(256)
__global__ void k_h(const float* __restrict__ x, const float* __restrict__ W,
                    unsigned short* __restrict__ hout) {
  __shared__ float As[CC][64];   // [c][nloc]
  __shared__ float Bs[CC][64];   // [c][hfloc]
  int bx = blockIdx.x;
  int b = bx >> 9;
  int nblk = (bx >> 3) & 63;
  int hfb = bx & 7;
  const float* xb = x + (size_t)b * CC * NN;
  int tid = threadIdx.x, tx = tid & 15, ty = tid >> 4;

  for (int i = tid; i < CC * 64; i += 256) {
    int c = i >> 6, r = i & 63;
    As[c][r] = xb[(size_t)c * NN + nblk * 64 + r];
    Bs[c][r] = W[(size_t)c * HF + hfb * 64 + r];
  }
  __syncthreads();

  float acc[4][4];
#pragma unroll
  for (int i = 0; i < 4; ++i)
#pragma unroll
    for (int j = 0; j < 4; ++j) acc[i][j] = 0.f;

#pragma unroll 8
  for (int c = 0; c < CC; ++c) {
    float4 a4 = *(const float4*)&As[c][ty * 4];
    float4 b4 = *(const float4*)&Bs[c][tx * 4];
    float av[4] = {a4.x, a4.y, a4.z, a4.w};
    float bv[4] = {b4.x, b4.y, b4.z, b4.w};
#pragma unroll
    for (int i = 0; i < 4; ++i)
#pragma unroll
      for (int j = 0; j < 4; ++j) acc[i][j] += av[i] * bv[j];
  }

#pragma unroll
  for (int i = 0; i < 4; ++i) {
    int row = nblk * 64 + ty * 4 + i;
    ushort4 v;
    v.x = f2bf(acc[i][0]); v.y = f2bf(acc[i][1]);
    v.z = f2bf(acc[i][2]); v.w = f2bf(acc[i][3]);
    *(ushort4*)&hout[((size_t)b * NN + row) * HF + hfb * 64 + tx * 4] = v;
  }
}

// ---------------------------------------------------------------------------
// a_src/a_dst[b][n][h] = sum_f h[b][n][h][f] * att_{src,dst}[h][f]
// one wave per node; lane covers 8 consecutive hf values
__global__ void k_att(const unsigned short* __restrict__ h,
                      const float* __restrict__ att_src, const float* __restrict__ att_dst,
                      float* __restrict__ a_src, float* __restrict__ a_dst) {
  int gid = blockIdx.x * 256 + threadIdx.x;
  int wid = gid >> 6;            // node index b*N+n
  int lane = threadIdx.x & 63;
  uint4 v = ((const uint4*)(h + (size_t)wid * HF))[lane];
  float hv[8];
  hv[0] = bf2f(v.x & 0xffff); hv[1] = bf2f(v.x >> 16);
  hv[2] = bf2f(v.y & 0xffff); hv[3] = bf2f(v.y >> 16);
  hv[4] = bf2f(v.z & 0xffff); hv[5] = bf2f(v.z >> 16);
  hv[6] = bf2f(v.w & 0xffff); hv[7] = bf2f(v.w >> 16);
  int base = lane * 8;
  float s = 0.f, d = 0.f;
#pragma unroll
  for (int i = 0; i < 8; ++i) {
    s += hv[i] * att_src[base + i];
    d += hv[i] * att_dst[base + i];
  }
#pragma unroll
  for (int off = 1; off < 16; off <<= 1) {
    s += __shfl_xor(s, off, 64);
    d += __shfl_xor(d, off, 64);
  }
  if ((lane & 15) == 0) {
    int hh = lane >> 4;
    a_src[wid * HH + hh] = s;
    a_dst[wid * HH + hh] = d;
  }
}

// ---------------------------------------------------------------------------
// gather + softmax(k=16) + weighted sum + head-mean + bias + transpose store
// one wave per node (16 nodes/wave serially); lane=(head hh, slot jj)
__launch_bounds__(256)
__global__ void k_out(const unsigned short* __restrict__ h, const int* __restrict__ nbr,
                      const float* __restrict__ a_src, const float* __restrict__ a_dst,
                      const float* __restrict__ bias, float* __restrict__ out) {
  __shared__ float Ot[FF][65];
  int b = blockIdx.x >> 6, nb = blockIdx.x & 63;
  int w = threadIdx.x >> 6, lane = threadIdx.x & 63;
  int hh = lane >> 4, jj = lane & 15;

  for (int t = 0; t < 16; ++t) {
    int nl = w * 16 + t;
    int node = b * NN + nb * 64 + nl;
    int mj = nbr[node * KK + jj];

    float e = a_src[((size_t)b * NN + mj) * HH + hh] + a_dst[(size_t)node * HH + hh];
    e = e >= 0.f ? e : 0.2f * e;
    float m = e;
#pragma unroll
    for (int off = 1; off < 16; off <<= 1) m = fmaxf(m, __shfl_xor(m, off, 64));
    float p = expf(e - m);
    float sum = p;
#pragma unroll
    for (int off = 1; off < 16; off <<= 1) sum += __shfl_xor(sum, off, 64);
    float alpha = p / sum;

    float acc[8];
#pragma unroll
    for (int i = 0; i < 8; ++i) acc[i] = 0.f;

#pragma unroll
    for (int j = 0; j < 16; ++j) {
      float aj = __shfl(alpha, (hh << 4) | j, 64);
      int m2 = __shfl(mj, j, 64);
      uint4 v = ((const uint4*)(h + (size_t)(b * NN + m2) * HF))[lane];
      acc[0] += aj * bf2f(v.x & 0xffff); acc[1] += aj * bf2f(v.x >> 16);
      acc[2] += aj * bf2f(v.y & 0xffff); acc[3] += aj * bf2f(v.y >> 16);
      acc[4] += aj * bf2f(v.z & 0xffff); acc[5] += aj * bf2f(v.z >> 16);
      acc[6] += aj * bf2f(v.w & 0xffff); acc[7] += aj * bf2f(v.w >> 16);
    }

    // mean over 4 heads (lanes differing in bits 4,5 share the same f-slice)
#pragma unroll
    for (int i = 0; i < 8; ++i) {
      acc[i] += __shfl_xor(acc[i], 16, 64);
      acc[i] += __shfl_xor(acc[i], 32, 64);
    }
    if (hh == 0) {
#pragma unroll
      for (int i = 0; i < 8; ++i) Ot[jj * 8 + i][nl] = acc[i] * 0.25f;
    }
  }
  __syncthreads();

  for (int i = threadIdx.x; i < FF * 64; i += 256) {
    int f = i >> 6, nl = i & 63;
    out[((size_t)b * FF + f) * NN + nb * 64 + nl] = Ot[f][nl] + bias[f];
  }
}

// ---------------------------------------------------------------------------
extern "C" void kernel_launch(void* const* d_in, const int* in_sizes, int n_in,
                              void* d_out, int out_size, void* d_ws, size_t ws_size,
                              hipStream_t stream) {
  const float* x       = (const float*)d_in[0];
  const float* W       = (const float*)d_in[1];
  const float* att_src = (const float*)d_in[2];
  const float* att_dst = (const float*)d_in[3];
  const float* bias    = (const float*)d_in[4];
  // d_in[5] is k (==16), baked into KK

  char* ws = (char*)d_ws;
  size_t off = 0;
  float* sq    = (float*)(ws + off); off += (size_t)BB * NN * 4;           // 128 KB
  int*   nbr   = (int*)(ws + off);   off += (size_t)BB * NN * KK * 4;      // 2 MB
  float* a_src = (float*)(ws + off); off += (size_t)BB * NN * HH * 4;      // 512 KB
  float* a_dst = (float*)(ws + off); off += (size_t)BB * NN * HH * 4;      // 512 KB
  unsigned short* h = (unsigned short*)(ws + off);
  off += (size_t)BB * NN * HF * 2;                                         // 33.5 MB
  // total ws needed ~36.9 MB

  float* out = (float*)d_out;

  k_sq <<<BB * NN / 256, 256, 0, stream>>>(x, sq);
  k_h  <<<BB * (NN / 64) * (HF / 64), 256, 0, stream>>>(x, W, h);
  k_knn<<<BB * (NN / 64), 256, 0, stream>>>(x, sq, nbr);
  k_att<<<BB * NN / 4, 256, 0, stream>>>(h, att_src, att_dst, a_src, a_dst);
  k_out<<<BB * (NN / 64), 256, 0, stream>>>(h, nbr, a_src, a_dst, bias, out);
}

// Round 3
// 628.442 us; speedup vs baseline: 2.0391x; 2.0391x over previous
//
#include <hip/hip_runtime.h>
#include <hip/hip_bf16.h>

#define BB 8
#define CC 128
#define NN 4096
#define HH 4
#define FF 128
#define KK 16
#define HF 512   // H*F

typedef __attribute__((ext_vector_type(8))) short short8v;
typedef __attribute__((ext_vector_type(8))) unsigned short ushort8v;
typedef __attribute__((ext_vector_type(4))) float f32x4;

__device__ __forceinline__ float bf2f(unsigned int u) {
  return __uint_as_float(u << 16);
}

__device__ __forceinline__ unsigned short f2bf(float f) {
  unsigned int u = __float_as_uint(f);
  unsigned int lsb = (u >> 16) & 1u;
  u += 0x7fffu + lsb;                 // RTNE
  return (unsigned short)(u >> 16);
}

__device__ __forceinline__ unsigned int umin2(unsigned int a, unsigned int b) {
  return a < b ? a : b;
}

// ---------------------------------------------------------------------------
// x[b][c][n] -> xt[b][n][c] (f32), xhi[b][n][c] (bf16), hsq[b][n] = 0.5*|x|^2
__launch_bounds__(256)
__global__ void k_split(const float* __restrict__ x,
                        float* __restrict__ xt,
                        unsigned short* __restrict__ xhi,
                        float* __restrict__ hsq) {
  __shared__ float Ls[CC][65];
  int b = blockIdx.x >> 6, nb = blockIdx.x & 63;
  int n0 = nb * 64;
  int tid = threadIdx.x;
  const float* xb = x + (size_t)b * CC * NN;

  for (int i = tid; i < CC * 64; i += 256) {
    int c = i >> 6, nl = i & 63;
    Ls[c][nl] = xb[(size_t)c * NN + n0 + nl];
  }
  __syncthreads();

  int n = tid >> 2, part = tid & 3;     // 64 n x 4 parts (32 c each)
  int node = b * NN + n0 + n;
  float sum = 0.f;
#pragma unroll
  for (int g = 0; g < 4; ++g) {
    float v[8];
    ushort8v ph;
#pragma unroll
    for (int j = 0; j < 8; ++j) {
      int c = part * 32 + g * 8 + j;
      v[j] = Ls[c][n];
      ph[j] = f2bf(v[j]);
      sum += v[j] * v[j];
    }
    float4 f0 = {v[0], v[1], v[2], v[3]};
    float4 f1 = {v[4], v[5], v[6], v[7]};
    *(float4*)&xt[(size_t)node * CC + part * 32 + g * 8] = f0;
    *(float4*)&xt[(size_t)node * CC + part * 32 + g * 8 + 4] = f1;
    *(ushort8v*)&xhi[(size_t)node * CC + part * 32 + g * 8] = ph;
  }
  sum += __shfl_xor(sum, 1, 64);
  sum += __shfl_xor(sum, 2, 64);
  if (part == 0) hsq[node] = 0.5f * sum;
}

// ---------------------------------------------------------------------------
// bf16 MFMA screen: per wave 16 queries, per lane top-16 (packed keys) of its
// 1024-candidate stream; dump 64 survivors/query for exact rerank.
// key = (bits(t+512) & ~1023) | (1023 - ordinal)  -- unique, tie->earlier idx
__launch_bounds__(256)
__global__ void k_screen(const unsigned short* __restrict__ xhi,
                         const float* __restrict__ hsq,
                         unsigned short* __restrict__ cand) {
  int b = blockIdx.x >> 6, qb = blockIdx.x & 63;
  int w = threadIdx.x >> 6, lane = threadIdx.x & 63;
  int qcol = lane & 15, kg = lane >> 4;
  int base = b * NN;
  int q = base + qb * 64 + w * 16 + qcol;

  const short8v* XH = (const short8v*)xhi;   // 16B granules: node*16 + g

  short8v bh0 = XH[(size_t)q * 16 + kg];
  short8v bh1 = XH[(size_t)q * 16 + 4 + kg];
  short8v bh2 = XH[(size_t)q * 16 + 8 + kg];
  short8v bh3 = XH[(size_t)q * 16 + 12 + kg];

  unsigned int bd[16];

  // prefill from tiles t=0..3 (16 candidates/lane)
#pragma unroll
  for (int t = 0; t < 4; ++t) {
    int mr = base + t * 16 + qcol;
    short8v ah0 = XH[(size_t)mr * 16 + kg];
    short8v ah1 = XH[(size_t)mr * 16 + 4 + kg];
    short8v ah2 = XH[(size_t)mr * 16 + 8 + kg];
    short8v ah3 = XH[(size_t)mr * 16 + 12 + kg];
    f32x4 acc = {0.f, 0.f, 0.f, 0.f};
    acc = __builtin_amdgcn_mfma_f32_16x16x32_bf16(ah0, bh0, acc, 0, 0, 0);
    acc = __builtin_amdgcn_mfma_f32_16x16x32_bf16(ah1, bh1, acc, 0, 0, 0);
    acc = __builtin_amdgcn_mfma_f32_16x16x32_bf16(ah2, bh2, acc, 0, 0, 0);
    acc = __builtin_amdgcn_mfma_f32_16x16x32_bf16(ah3, bh3, acc, 0, 0, 0);
    float4 hs = *(const float4*)&hsq[base + t * 16 + kg * 4];
    float hsa[4] = {hs.x, hs.y, hs.z, hs.w};
#pragma unroll
    for (int r = 0; r < 4; ++r) {
      float tv = acc[r] - hsa[r] + 512.0f;
      bd[t * 4 + r] = (__float_as_uint(tv) & ~1023u) | (1023u - (unsigned)(t * 4 + r));
    }
  }
  unsigned int m0 = umin2(umin2(umin2(bd[0], bd[1]), umin2(bd[2], bd[3])),
                          umin2(umin2(bd[4], bd[5]), umin2(bd[6], bd[7])));
  unsigned int m1 = umin2(umin2(umin2(bd[8], bd[9]), umin2(bd[10], bd[11])),
                          umin2(umin2(bd[12], bd[13]), umin2(bd[14], bd[15])));
  unsigned int worst = umin2(m0, m1);

#pragma unroll 1
  for (int t = 4; t < 256; ++t) {
    int mr = base + t * 16 + qcol;
    short8v ah0 = XH[(size_t)mr * 16 + kg];
    short8v ah1 = XH[(size_t)mr * 16 + 4 + kg];
    short8v ah2 = XH[(size_t)mr * 16 + 8 + kg];
    short8v ah3 = XH[(size_t)mr * 16 + 12 + kg];
    f32x4 acc = {0.f, 0.f, 0.f, 0.f};
    acc = __builtin_amdgcn_mfma_f32_16x16x32_bf16(ah0, bh0, acc, 0, 0, 0);
    acc = __builtin_amdgcn_mfma_f32_16x16x32_bf16(ah1, bh1, acc, 0, 0, 0);
    acc = __builtin_amdgcn_mfma_f32_16x16x32_bf16(ah2, bh2, acc, 0, 0, 0);
    acc = __builtin_amdgcn_mfma_f32_16x16x32_bf16(ah3, bh3, acc, 0, 0, 0);
    float4 hs = *(const float4*)&hsq[base + t * 16 + kg * 4];
    float hsa[4] = {hs.x, hs.y, hs.z, hs.w};
#pragma unroll
    for (int r = 0; r < 4; ++r) {
      float tv = acc[r] - hsa[r] + 512.0f;
      unsigned int key = (__float_as_uint(tv) & ~1023u) | (1023u - (unsigned)(t * 4 + r));
      if (key > worst) {
#pragma unroll
        for (int i = 0; i < 16; ++i) bd[i] = (bd[i] == worst) ? key : bd[i];
        unsigned int n0_ = umin2(umin2(umin2(bd[0], bd[1]), umin2(bd[2], bd[3])),
                                 umin2(umin2(bd[4], bd[5]), umin2(bd[6], bd[7])));
        unsigned int n1_ = umin2(umin2(umin2(bd[8], bd[9]), umin2(bd[10], bd[11])),
                                 umin2(umin2(bd[12], bd[13]), umin2(bd[14], bd[15])));
        worst = umin2(n0_, n1_);
      }
    }
  }

  // decode ordinals -> global candidate indices, dump 16 per lane
  unsigned short* o = cand + (size_t)q * 64 + kg * 16;
#pragma unroll
  for (int i = 0; i < 16; ++i) {
    unsigned int s = 1023u - (bd[i] & 1023u);
    o[i] = (unsigned short)((s >> 2) * 16 + kg * 4 + (s & 3));
  }
}

// ---------------------------------------------------------------------------
// Exact f32 rerank of 64 survivors -> top-16 (val desc, idx asc tie-break)
__launch_bounds__(256)
__global__ void k_rerank(const float* __restrict__ xt, const float* __restrict__ hsq,
                         const unsigned short* __restrict__ cand, int* __restrict__ nbr) {
  int gid = blockIdx.x * 256 + threadIdx.x;
  int wq = gid >> 6;                  // global query id
  int lane = threadIdx.x & 63;
  int b = wq >> 12;
  int base = b * NN;
  int ci = cand[(size_t)wq * 64 + lane];
  const float* qr = xt + (size_t)wq * CC;
  const float* cr = xt + (size_t)(base + ci) * CC;
  float acc = 0.f;
#pragma unroll
  for (int c = 0; c < CC; c += 4) {
    float4 qa = *(const float4*)&qr[c];
    float4 ca = *(const float4*)&cr[c];
    acc = fmaf(qa.x, ca.x, acc);
    acc = fmaf(qa.y, ca.y, acc);
    acc = fmaf(qa.z, ca.z, acc);
    acc = fmaf(qa.w, ca.w, acc);
  }
  float myv = acc - hsq[base + ci];
  int myi = ci;
  bool alive = true;
  int* o = nbr + (size_t)wq * KK;
  for (int s = 0; s < KK; ++s) {
    float v = alive ? myv : -3.4e38f;
    int i = alive ? myi : 0x7fffffff;
#pragma unroll
    for (int off = 1; off < 64; off <<= 1) {
      float ov = __shfl_xor(v, off, 64);
      int oi = __shfl_xor(i, off, 64);
      bool take = (ov > v) || (ov == v && oi < i);
      v = take ? ov : v;
      i = take ? oi : i;
    }
    if (lane == 0) o[s] = i;
    if (i == myi) alive = false;
  }
}

// ---------------------------------------------------------------------------
// h[b][n][hf] = sum_c x[b][c][n] * W[c][hf], stored bf16
__launch_bounds__(256)
__global__ void k_h(const float* __restrict__ x, const float* __restrict__ W,
                    unsigned short* __restrict__ hout) {
  __shared__ float As[CC][64];   // [c][nloc]
  __shared__ float Bs[CC][64];   // [c][hfloc]
  int bx = blockIdx.x;
  int b = bx >> 9;
  int nblk = (bx >> 3) & 63;
  int hfb = bx & 7;
  const float* xb = x + (size_t)b * CC * NN;
  int tid = threadIdx.x, tx = tid & 15, ty = tid >> 4;

  for (int i = tid; i < CC * 64; i += 256) {
    int c = i >> 6, r = i & 63;
    As[c][r] = xb[(size_t)c * NN + nblk * 64 + r];
    Bs[c][r] = W[(size_t)c * HF + hfb * 64 + r];
  }
  __syncthreads();

  float acc[4][4];
#pragma unroll
  for (int i = 0; i < 4; ++i)
#pragma unroll
    for (int j = 0; j < 4; ++j) acc[i][j] = 0.f;

#pragma unroll 8
  for (int c = 0; c < CC; ++c) {
    float4 a4 = *(const float4*)&As[c][ty * 4];
    float4 b4 = *(const float4*)&Bs[c][tx * 4];
    float av[4] = {a4.x, a4.y, a4.z, a4.w};
    float bv[4] = {b4.x, b4.y, b4.z, b4.w};
#pragma unroll
    for (int i = 0; i < 4; ++i)
#pragma unroll
      for (int j = 0; j < 4; ++j) acc[i][j] += av[i] * bv[j];
  }

#pragma unroll
  for (int i = 0; i < 4; ++i) {
    int row = nblk * 64 + ty * 4 + i;
    ushort4 v;
    v.x = f2bf(acc[i][0]); v.y = f2bf(acc[i][1]);
    v.z = f2bf(acc[i][2]); v.w = f2bf(acc[i][3]);
    *(ushort4*)&hout[((size_t)b * NN + row) * HF + hfb * 64 + tx * 4] = v;
  }
}

// ---------------------------------------------------------------------------
// a_src/a_dst[b][n][h] = sum_f h[b][n][h][f] * att_{src,dst}[h][f]
__global__ void k_att(const unsigned short* __restrict__ h,
                      const float* __restrict__ att_src, const float* __restrict__ att_dst,
                      float* __restrict__ a_src, float* __restrict__ a_dst) {
  int gid = blockIdx.x * 256 + threadIdx.x;
  int wid = gid >> 6;            // node index b*N+n
  int lane = threadIdx.x & 63;
  uint4 v = ((const uint4*)(h + (size_t)wid * HF))[lane];
  float hv[8];
  hv[0] = bf2f(v.x & 0xffff); hv[1] = bf2f(v.x >> 16);
  hv[2] = bf2f(v.y & 0xffff); hv[3] = bf2f(v.y >> 16);
  hv[4] = bf2f(v.z & 0xffff); hv[5] = bf2f(v.z >> 16);
  hv[6] = bf2f(v.w & 0xffff); hv[7] = bf2f(v.w >> 16);
  int base = lane * 8;
  float s = 0.f, d = 0.f;
#pragma unroll
  for (int i = 0; i < 8; ++i) {
    s += hv[i] * att_src[base + i];
    d += hv[i] * att_dst[base + i];
  }
#pragma unroll
  for (int off = 1; off < 16; off <<= 1) {
    s += __shfl_xor(s, off, 64);
    d += __shfl_xor(d, off, 64);
  }
  if ((lane & 15) == 0) {
    int hh = lane >> 4;
    a_src[wid * HH + hh] = s;
    a_dst[wid * HH + hh] = d;
  }
}

// ---------------------------------------------------------------------------
// gather + softmax(k=16) + weighted sum + head-mean + bias + transpose store
__launch_bounds__(256)
__global__ void k_out(const unsigned short* __restrict__ h, const int* __restrict__ nbr,
                      const float* __restrict__ a_src, const float* __restrict__ a_dst,
                      const float* __restrict__ bias, float* __restrict__ out) {
  __shared__ float Ot[FF][65];
  int b = blockIdx.x >> 6, nb = blockIdx.x & 63;
  int w = threadIdx.x >> 6, lane = threadIdx.x & 63;
  int hh = lane >> 4, jj = lane & 15;

  for (int t = 0; t < 16; ++t) {
    int nl = w * 16 + t;
    int node = b * NN + nb * 64 + nl;
    int mj = nbr[node * KK + jj];

    float e = a_src[((size_t)b * NN + mj) * HH + hh] + a_dst[(size_t)node * HH + hh];
    e = e >= 0.f ? e : 0.2f * e;
    float m = e;
#pragma unroll
    for (int off = 1; off < 16; off <<= 1) m = fmaxf(m, __shfl_xor(m, off, 64));
    float p = expf(e - m);
    float sum = p;
#pragma unroll
    for (int off = 1; off < 16; off <<= 1) sum += __shfl_xor(sum, off, 64);
    float alpha = p / sum;

    float acc[8];
#pragma unroll
    for (int i = 0; i < 8; ++i) acc[i] = 0.f;

#pragma unroll
    for (int j = 0; j < 16; ++j) {
      float aj = __shfl(alpha, (hh << 4) | j, 64);
      int m2 = __shfl(mj, j, 64);
      uint4 v = ((const uint4*)(h + (size_t)(b * NN + m2) * HF))[lane];
      acc[0] += aj * bf2f(v.x & 0xffff); acc[1] += aj * bf2f(v.x >> 16);
      acc[2] += aj * bf2f(v.y & 0xffff); acc[3] += aj * bf2f(v.y >> 16);
      acc[4] += aj * bf2f(v.z & 0xffff); acc[5] += aj * bf2f(v.z >> 16);
      acc[6] += aj * bf2f(v.w & 0xffff); acc[7] += aj * bf2f(v.w >> 16);
    }

#pragma unroll
    for (int i = 0; i < 8; ++i) {
      acc[i] += __shfl_xor(acc[i], 16, 64);
      acc[i] += __shfl_xor(acc[i], 32, 64);
    }
    if (hh == 0) {
#pragma unroll
      for (int i = 0; i < 8; ++i) Ot[jj * 8 + i][nl] = acc[i] * 0.25f;
    }
  }
  __syncthreads();

  for (int i = threadIdx.x; i < FF * 64; i += 256) {
    int f = i >> 6, nl = i & 63;
    out[((size_t)b * FF + f) * NN + nb * 64 + nl] = Ot[f][nl] + bias[f];
  }
}

// ---------------------------------------------------------------------------
extern "C" void kernel_launch(void* const* d_in, const int* in_sizes, int n_in,
                              void* d_out, int out_size, void* d_ws, size_t ws_size,
                              hipStream_t stream) {
  const float* x       = (const float*)d_in[0];
  const float* W       = (const float*)d_in[1];
  const float* att_src = (const float*)d_in[2];
  const float* att_dst = (const float*)d_in[3];
  const float* bias    = (const float*)d_in[4];

  char* ws = (char*)d_ws;
  // region0 (33.55 MB) is time-shared:
  //   phase A (knn): xt (16.78M) | xhi (8.39M) | cand (4.19M)
  //   phase B (gat): h (33.55M)   -- k_h runs after k_rerank's last read
  float* xt            = (float*)ws;
  unsigned short* xhi  = (unsigned short*)(ws + 16777216);
  unsigned short* cand = (unsigned short*)(ws + 16777216 + 8388608);
  unsigned short* h    = (unsigned short*)ws;
  size_t tail = 33554432;
  int*   nbr   = (int*)(ws + tail);   tail += (size_t)BB * NN * KK * 4;   // 2 MB
  float* hsq   = (float*)(ws + tail); tail += (size_t)BB * NN * 4;        // 128 KB
  float* a_src = (float*)(ws + tail); tail += (size_t)BB * NN * HH * 4;   // 512 KB
  float* a_dst = (float*)(ws + tail); tail += (size_t)BB * NN * HH * 4;   // 512 KB
  // total 36.8 MB

  float* out = (float*)d_out;

  k_split <<<BB * (NN / 64), 256, 0, stream>>>(x, xt, xhi, hsq);
  k_screen<<<BB * (NN / 64), 256, 0, stream>>>(xhi, hsq, cand);
  k_rerank<<<BB * NN / 4, 256, 0, stream>>>(xt, hsq, cand, nbr);
  k_h     <<<BB * (NN / 64) * (HF / 64), 256, 0, stream>>>(x, W, h);
  k_att   <<<BB * NN / 4, 256, 0, stream>>>(h, att_src, att_dst, a_src, a_dst);
  k_out   <<<BB * (NN / 64), 256, 0, stream>>>(h, nbr, a_src, a_dst, bias, out);
}

// Round 4
// 556.205 us; speedup vs baseline: 2.3039x; 1.1299x over previous
//
#include <hip/hip_runtime.h>
#include <hip/hip_bf16.h>

#define BB 8
#define CC 128
#define NN 4096
#define HH 4
#define FF 128
#define KK 16
#define HF 512   // H*F

typedef __attribute__((ext_vector_type(8))) short short8v;
typedef __attribute__((ext_vector_type(8))) unsigned short ushort8v;
typedef __attribute__((ext_vector_type(4))) float f32x4;

__device__ __forceinline__ float bf2f(unsigned int u) {
  return __uint_as_float(u << 16);
}

__device__ __forceinline__ unsigned short f2bf(float f) {
  unsigned int u = __float_as_uint(f);
  unsigned int lsb = (u >> 16) & 1u;
  u += 0x7fffu + lsb;                 // RTNE
  return (unsigned short)(u >> 16);
}

__device__ __forceinline__ unsigned int umin2(unsigned int a, unsigned int b) {
  return a < b ? a : b;
}
__device__ __forceinline__ unsigned int umin3(unsigned int a, unsigned int b, unsigned int c) {
  return umin2(umin2(a, b), c);       // should fuse to v_min3_u32
}

// ---------------------------------------------------------------------------
// x[b][c][n] -> xt[b][n][c] (f32), xhi[b][n][c] (bf16), hsq[b][n] = 0.5*|x|^2
__launch_bounds__(256)
__global__ void k_split(const float* __restrict__ x,
                        float* __restrict__ xt,
                        unsigned short* __restrict__ xhi,
                        float* __restrict__ hsq) {
  __shared__ float Ls[CC][65];
  int b = blockIdx.x >> 6, nb = blockIdx.x & 63;
  int n0 = nb * 64;
  int tid = threadIdx.x;
  const float* xb = x + (size_t)b * CC * NN;

  for (int i = tid; i < CC * 64; i += 256) {
    int c = i >> 6, nl = i & 63;
    Ls[c][nl] = xb[(size_t)c * NN + n0 + nl];
  }
  __syncthreads();

  int n = tid >> 2, part = tid & 3;     // 64 n x 4 parts (32 c each)
  int node = b * NN + n0 + n;
  float sum = 0.f;
#pragma unroll
  for (int g = 0; g < 4; ++g) {
    float v[8];
    ushort8v ph;
#pragma unroll
    for (int j = 0; j < 8; ++j) {
      int c = part * 32 + g * 8 + j;
      v[j] = Ls[c][n];
      ph[j] = f2bf(v[j]);
      sum += v[j] * v[j];
    }
    float4 f0 = {v[0], v[1], v[2], v[3]};
    float4 f1 = {v[4], v[5], v[6], v[7]};
    *(float4*)&xt[(size_t)node * CC + part * 32 + g * 8] = f0;
    *(float4*)&xt[(size_t)node * CC + part * 32 + g * 8 + 4] = f1;
    *(ushort8v*)&xhi[(size_t)node * CC + part * 32 + g * 8] = ph;
  }
  sum += __shfl_xor(sum, 1, 64);
  sum += __shfl_xor(sum, 2, 64);
  if (part == 0) hsq[node] = 0.5f * sum;
}

// ---------------------------------------------------------------------------
// Pack W[c][hf] f32 -> Whi/Wlo[hf][c] bf16 (row-major; granule order matches
// the MFMA fragment loads: granule g of row hf covers c = g*8 .. g*8+7)
__global__ void k_wpack(const float* __restrict__ W,
                        unsigned short* __restrict__ Whi,
                        unsigned short* __restrict__ Wlo) {
  int i = blockIdx.x * 256 + threadIdx.x;   // over 512*128
  int hf = i >> 7, c = i & 127;
  float v = W[(size_t)c * HF + hf];
  unsigned short hb = f2bf(v);
  Whi[i] = hb;
  Wlo[i] = f2bf(v - bf2f(hb));
}

// ---------------------------------------------------------------------------
// bf16 MFMA screen over one candidate HALF (2048 cands) per block.
// Per wave 16 queries; per lane top-16 packed keys of its 512-substream.
// key = (bits(t+512) & ~1023) | (1023 - local_ordinal); dumps keys + indices.
__launch_bounds__(256)
__global__ void k_screen(const unsigned short* __restrict__ xhi,
                         const float* __restrict__ hsq,
                         unsigned short* __restrict__ cand,
                         unsigned int* __restrict__ keys) {
  int bx = blockIdx.x;
  int b = bx >> 7, rest = bx & 127;
  int qb = rest >> 1, half = rest & 1;
  int w = threadIdx.x >> 6, lane = threadIdx.x & 63;
  int qcol = lane & 15, kg = lane >> 4;
  int base = b * NN;
  int q = base + qb * 64 + w * 16 + qcol;
  int t0 = half * 128;

  const short8v* XH = (const short8v*)xhi;   // 16B granules: node*16 + ks*4 + kg

  short8v bh0 = XH[(size_t)q * 16 + kg];
  short8v bh1 = XH[(size_t)q * 16 + 4 + kg];
  short8v bh2 = XH[(size_t)q * 16 + 8 + kg];
  short8v bh3 = XH[(size_t)q * 16 + 12 + kg];

  unsigned int bd[16];

  // prefill from local tiles 0..3 (16 candidates/lane)
#pragma unroll
  for (int lt = 0; lt < 4; ++lt) {
    int mr = base + (t0 + lt) * 16 + qcol;
    short8v ah0 = XH[(size_t)mr * 16 + kg];
    short8v ah1 = XH[(size_t)mr * 16 + 4 + kg];
    short8v ah2 = XH[(size_t)mr * 16 + 8 + kg];
    short8v ah3 = XH[(size_t)mr * 16 + 12 + kg];
    f32x4 acc = {0.f, 0.f, 0.f, 0.f};
    acc = __builtin_amdgcn_mfma_f32_16x16x32_bf16(ah0, bh0, acc, 0, 0, 0);
    acc = __builtin_amdgcn_mfma_f32_16x16x32_bf16(ah1, bh1, acc, 0, 0, 0);
    acc = __builtin_amdgcn_mfma_f32_16x16x32_bf16(ah2, bh2, acc, 0, 0, 0);
    acc = __builtin_amdgcn_mfma_f32_16x16x32_bf16(ah3, bh3, acc, 0, 0, 0);
    float4 hs = *(const float4*)&hsq[base + (t0 + lt) * 16 + kg * 4];
    float hsa[4] = {hs.x, hs.y, hs.z, hs.w};
#pragma unroll
    for (int r = 0; r < 4; ++r) {
      float tv = acc[r] - hsa[r] + 512.0f;
      bd[lt * 4 + r] = (__float_as_uint(tv) & ~1023u) | (1023u - (unsigned)(lt * 4 + r));
    }
  }
  unsigned int m0 = umin3(bd[0], bd[1], bd[2]);
  m0 = umin3(m0, bd[3], bd[4]);
  m0 = umin3(m0, bd[5], bd[6]);
  m0 = umin2(m0, bd[7]);
  unsigned int m1 = umin3(bd[8], bd[9], bd[10]);
  m1 = umin3(m1, bd[11], bd[12]);
  m1 = umin3(m1, bd[13], bd[14]);
  m1 = umin2(m1, bd[15]);
  unsigned int worst = umin2(m0, m1);

#pragma unroll 1
  for (int lt = 4; lt < 128; ++lt) {
    int mr = base + (t0 + lt) * 16 + qcol;
    short8v ah0 = XH[(size_t)mr * 16 + kg];
    short8v ah1 = XH[(size_t)mr * 16 + 4 + kg];
    short8v ah2 = XH[(size_t)mr * 16 + 8 + kg];
    short8v ah3 = XH[(size_t)mr * 16 + 12 + kg];
    f32x4 acc = {0.f, 0.f, 0.f, 0.f};
    acc = __builtin_amdgcn_mfma_f32_16x16x32_bf16(ah0, bh0, acc, 0, 0, 0);
    acc = __builtin_amdgcn_mfma_f32_16x16x32_bf16(ah1, bh1, acc, 0, 0, 0);
    acc = __builtin_amdgcn_mfma_f32_16x16x32_bf16(ah2, bh2, acc, 0, 0, 0);
    acc = __builtin_amdgcn_mfma_f32_16x16x32_bf16(ah3, bh3, acc, 0, 0, 0);
    float4 hs = *(const float4*)&hsq[base + (t0 + lt) * 16 + kg * 4];
    float hsa[4] = {hs.x, hs.y, hs.z, hs.w};
#pragma unroll
    for (int r = 0; r < 4; ++r) {
      float tv = acc[r] - hsa[r] + 512.0f;
      unsigned int key = (__float_as_uint(tv) & ~1023u) | (1023u - (unsigned)(lt * 4 + r));
      if (key > worst) {
#pragma unroll
        for (int i = 0; i < 16; ++i) bd[i] = (bd[i] == worst) ? key : bd[i];
        unsigned int n0_ = umin3(bd[0], bd[1], bd[2]);
        n0_ = umin3(n0_, bd[3], bd[4]);
        n0_ = umin3(n0_, bd[5], bd[6]);
        n0_ = umin2(n0_, bd[7]);
        unsigned int n1_ = umin3(bd[8], bd[9], bd[10]);
        n1_ = umin3(n1_, bd[11], bd[12]);
        n1_ = umin3(n1_, bd[13], bd[14]);
        n1_ = umin2(n1_, bd[15]);
        worst = umin2(n0_, n1_);
      }
    }
  }

  // dump keys + decoded indices: slot = q*128 + half*64 + kg*16 + i
  unsigned short* oc = cand + (size_t)q * 128 + half * 64 + kg * 16;
  unsigned int* ok = keys + (size_t)q * 128 + half * 64 + kg * 16;
#pragma unroll
  for (int i = 0; i < 16; ++i) {
    unsigned int s = 1023u - (bd[i] & 1023u);
    oc[i] = (unsigned short)((t0 + (int)(s >> 2)) * 16 + kg * 4 + (int)(s & 3));
    ok[i] = bd[i];
  }
}

// ---------------------------------------------------------------------------
// Rerank: find 16th-best screen key (tau), exact f32 dot only for cands with
// key >= tau - 1.0 (14-sigma margin), then exact top-16 (val desc, idx asc).
__launch_bounds__(256)
__global__ void k_rerank(const float* __restrict__ xt, const float* __restrict__ hsq,
                         const unsigned short* __restrict__ cand,
                         const unsigned int* __restrict__ keys,
                         int* __restrict__ nbr) {
  int wq = blockIdx.x * 4 + (threadIdx.x >> 6);
  int lane = threadIdx.x & 63;
  int b = wq >> 12;
  int base = b * NN;
  unsigned int k0 = keys[(size_t)wq * 128 + lane];
  unsigned int k1 = keys[(size_t)wq * 128 + 64 + lane];
  int c0 = cand[(size_t)wq * 128 + lane];
  int c1 = cand[(size_t)wq * 128 + 64 + lane];

  // --- tau = 16th-largest key across the 128 ---
  unsigned int s0 = k0 > k1 ? k0 : k1;
  unsigned int s1 = k0 > k1 ? k1 : k0;
  unsigned int tau = 0;
  for (int s = 0; s < KK; ++s) {
    unsigned int m = s0;
#pragma unroll
    for (int off = 1; off < 64; off <<= 1) {
      unsigned int o = __shfl_xor(m, off, 64);
      m = o > m ? o : m;
    }
    unsigned long long own = __ballot(s0 == m);
    int first = (int)__ffsll(own) - 1;
    if (lane == first) { s0 = s1; s1 = 0; }
    tau = m;
  }
  float thr = __uint_as_float(tau & ~1023u) - 1.0f;
  bool p0 = __uint_as_float(k0 & ~1023u) >= thr;
  bool p1 = __uint_as_float(k1 & ~1023u) >= thr;

  const float* qr = xt + (size_t)wq * CC;
  float v0 = -3.4e38f, v1 = -3.4e38f;
  if (p0) {
    const float* cr = xt + (size_t)(base + c0) * CC;
    float acc = 0.f;
#pragma unroll
    for (int c = 0; c < CC; c += 4) {
      float4 qa = *(const float4*)&qr[c];
      float4 ca = *(const float4*)&cr[c];
      acc = fmaf(qa.x, ca.x, acc);
      acc = fmaf(qa.y, ca.y, acc);
      acc = fmaf(qa.z, ca.z, acc);
      acc = fmaf(qa.w, ca.w, acc);
    }
    v0 = acc - hsq[base + c0];
  }
  if (p1) {
    const float* cr = xt + (size_t)(base + c1) * CC;
    float acc = 0.f;
#pragma unroll
    for (int c = 0; c < CC; c += 4) {
      float4 qa = *(const float4*)&qr[c];
      float4 ca = *(const float4*)&cr[c];
      acc = fmaf(qa.x, ca.x, acc);
      acc = fmaf(qa.y, ca.y, acc);
      acc = fmaf(qa.z, ca.z, acc);
      acc = fmaf(qa.w, ca.w, acc);
    }
    v1 = acc - hsq[base + c1];
  }

  int i0 = c0, i1 = c1;
  bool sw = (v1 > v0) || (v1 == v0 && i1 < i0);
  if (sw) {
    float tv = v0; v0 = v1; v1 = tv;
    int ti = i0; i0 = i1; i1 = ti;
  }
  int* o = nbr + (size_t)wq * KK;
  for (int s = 0; s < KK; ++s) {
    float wv = v0; int wi = i0;
#pragma unroll
    for (int off = 1; off < 64; off <<= 1) {
      float ov = __shfl_xor(wv, off, 64);
      int oi = __shfl_xor(wi, off, 64);
      bool take = (ov > wv) || (ov == wv && oi < wi);
      wv = take ? ov : wv;
      wi = take ? oi : wi;
    }
    if (lane == 0) o[s] = wi;
    if (i0 == wi) {
      v0 = v1; i0 = i1;
      v1 = -3.4e38f; i1 = 0x7fffffff;
    }
  }
}

// ---------------------------------------------------------------------------
// h = xt . W via 3-term split-bf16 MFMA (xhi*Whi + xhi*Wlo + xlo*Whi), bf16 out
__launch_bounds__(256)
__global__ void k_h2(const float* __restrict__ xt,
                     const unsigned short* __restrict__ Whi,
                     const unsigned short* __restrict__ Wlo,
                     unsigned short* __restrict__ hout) {
  int w = threadIdx.x >> 6, lane = threadIdx.x & 63;
  int r16 = lane & 15, kg = lane >> 4;
  int nd0 = blockIdx.x * 64 + w * 16;
  const float* arow = xt + (size_t)(nd0 + r16) * CC;
  short8v ahi[4], alo[4];
#pragma unroll
  for (int ks = 0; ks < 4; ++ks) {
    float4 f0 = *(const float4*)&arow[ks * 32 + kg * 8];
    float4 f1 = *(const float4*)&arow[ks * 32 + kg * 8 + 4];
    float fv[8] = {f0.x, f0.y, f0.z, f0.w, f1.x, f1.y, f1.z, f1.w};
    short8v hh_, ll_;
#pragma unroll
    for (int j = 0; j < 8; ++j) {
      unsigned short hb = f2bf(fv[j]);
      hh_[j] = (short)hb;
      ll_[j] = (short)f2bf(fv[j] - bf2f(hb));
    }
    ahi[ks] = hh_; alo[ks] = ll_;
  }
  const short8v* WH = (const short8v*)Whi;   // granule: hf*16 + ks*4 + kg
  const short8v* WL = (const short8v*)Wlo;
#pragma unroll 1
  for (int ct = 0; ct < 32; ++ct) {
    int hf = ct * 16 + r16;
    f32x4 acc = {0.f, 0.f, 0.f, 0.f};
#pragma unroll
    for (int ks = 0; ks < 4; ++ks) {
      short8v bh = WH[(size_t)hf * 16 + ks * 4 + kg];
      short8v bl = WL[(size_t)hf * 16 + ks * 4 + kg];
      acc = __builtin_amdgcn_mfma_f32_16x16x32_bf16(ahi[ks], bh, acc, 0, 0, 0);
      acc = __builtin_amdgcn_mfma_f32_16x16x32_bf16(ahi[ks], bl, acc, 0, 0, 0);
      acc = __builtin_amdgcn_mfma_f32_16x16x32_bf16(alo[ks], bh, acc, 0, 0, 0);
    }
#pragma unroll
    for (int r = 0; r < 4; ++r)
      hout[(size_t)(nd0 + kg * 4 + r) * HF + hf] = f2bf(acc[r]);
  }
}

// ---------------------------------------------------------------------------
// a_src/a_dst[b][n][h] = sum_f h[b][n][h][f] * att_{src,dst}[h][f]
__global__ void k_att(const unsigned short* __restrict__ h,
                      const float* __restrict__ att_src, const float* __restrict__ att_dst,
                      float* __restrict__ a_src, float* __restrict__ a_dst) {
  int gid = blockIdx.x * 256 + threadIdx.x;
  int wid = gid >> 6;            // node index b*N+n
  int lane = threadIdx.x & 63;
  uint4 v = ((const uint4*)(h + (size_t)wid * HF))[lane];
  float hv[8];
  hv[0] = bf2f(v.x & 0xffff); hv[1] = bf2f(v.x >> 16);
  hv[2] = bf2f(v.y & 0xffff); hv[3] = bf2f(v.y >> 16);
  hv[4] = bf2f(v.z & 0xffff); hv[5] = bf2f(v.z >> 16);
  hv[6] = bf2f(v.w & 0xffff); hv[7] = bf2f(v.w >> 16);
  int base = lane * 8;
  float s = 0.f, d = 0.f;
#pragma unroll
  for (int i = 0; i < 8; ++i) {
    s += hv[i] * att_src[base + i];
    d += hv[i] * att_dst[base + i];
  }
#pragma unroll
  for (int off = 1; off < 16; off <<= 1) {
    s += __shfl_xor(s, off, 64);
    d += __shfl_xor(d, off, 64);
  }
  if ((lane & 15) == 0) {
    int hh = lane >> 4;
    a_src[wid * HH + hh] = s;
    a_dst[wid * HH + hh] = d;
  }
}

// ---------------------------------------------------------------------------
// gather + softmax(k=16) + weighted sum + head-mean + bias + transpose store
// 16 nodes per block (grid 2048 -> 8 blocks/CU)
__launch_bounds__(256)
__global__ void k_out(const unsigned short* __restrict__ h, const int* __restrict__ nbr,
                      const float* __restrict__ a_src, const float* __restrict__ a_dst,
                      const float* __restrict__ bias, float* __restrict__ out) {
  __shared__ float Ot[FF][17];
  int b = blockIdx.x >> 8, nb = blockIdx.x & 255;
  int w = threadIdx.x >> 6, lane = threadIdx.x & 63;
  int hh = lane >> 4, jj = lane & 15;

  for (int t = 0; t < 4; ++t) {
    int nl = w * 4 + t;
    int node = b * NN + nb * 16 + nl;
    int mj = nbr[node * KK + jj];

    float e = a_src[((size_t)b * NN + mj) * HH + hh] + a_dst[(size_t)node * HH + hh];
    e = e >= 0.f ? e : 0.2f * e;
    float m = e;
#pragma unroll
    for (int off = 1; off < 16; off <<= 1) m = fmaxf(m, __shfl_xor(m, off, 64));
    float p = expf(e - m);
    float sum = p;
#pragma unroll
    for (int off = 1; off < 16; off <<= 1) sum += __shfl_xor(sum, off, 64);
    float alpha = p / sum;

    float acc[8];
#pragma unroll
    for (int i = 0; i < 8; ++i) acc[i] = 0.f;

#pragma unroll
    for (int j = 0; j < 16; ++j) {
      float aj = __shfl(alpha, (hh << 4) | j, 64);
      int m2 = __shfl(mj, j, 64);
      uint4 v = ((const uint4*)(h + (size_t)(b * NN + m2) * HF))[lane];
      acc[0] += aj * bf2f(v.x & 0xffff); acc[1] += aj * bf2f(v.x >> 16);
      acc[2] += aj * bf2f(v.y & 0xffff); acc[3] += aj * bf2f(v.y >> 16);
      acc[4] += aj * bf2f(v.z & 0xffff); acc[5] += aj * bf2f(v.z >> 16);
      acc[6] += aj * bf2f(v.w & 0xffff); acc[7] += aj * bf2f(v.w >> 16);
    }

#pragma unroll
    for (int i = 0; i < 8; ++i) {
      acc[i] += __shfl_xor(acc[i], 16, 64);
      acc[i] += __shfl_xor(acc[i], 32, 64);
    }
    if (hh == 0) {
#pragma unroll
      for (int i = 0; i < 8; ++i) Ot[jj * 8 + i][nl] = acc[i] * 0.25f;
    }
  }
  __syncthreads();

#pragma unroll
  for (int it = 0; it < 8; ++it) {
    int idx = it * 256 + threadIdx.x;
    int f = idx >> 4, nl = idx & 15;
    out[((size_t)b * FF + f) * NN + nb * 16 + nl] = Ot[f][nl] + bias[f];
  }
}

// ---------------------------------------------------------------------------
extern "C" void kernel_launch(void* const* d_in, const int* in_sizes, int n_in,
                              void* d_out, int out_size, void* d_ws, size_t ws_size,
                              hipStream_t stream) {
  const float* x       = (const float*)d_in[0];
  const float* W       = (const float*)d_in[1];
  const float* att_src = (const float*)d_in[2];
  const float* att_dst = (const float*)d_in[3];
  const float* bias    = (const float*)d_in[4];

  char* ws = (char*)d_ws;
  // Lifetime-aliased layout (total 53,477,376 B < proven 53.6 MB):
  //   [0        ,16777216): xt   (f32)   — live: split .. rerank,h2
  //   [16777216 ,25165824): xhi  (bf16)  — live: split .. screen
  //   [25165824 ,33554432): cand (u16)   — live: screen .. rerank
  //   [33554432 ,50331648): keys (u32)   — live: screen .. rerank
  //   [16777216 ,50331648): h    (bf16)  — written by k_h2 AFTER rerank
  //   [50331648 ,52428800): nbr  (i32)   — live: rerank .. out
  //   [52428800 ,52953088): a_src (f32)  — aliased early by Whi/Wlo (wpack..h2)
  //   [52953088 ,53477376): a_dst (f32)  — aliased early by hsq (split..rerank)
  float* xt            = (float*)ws;
  unsigned short* xhi  = (unsigned short*)(ws + 16777216);
  unsigned short* cand = (unsigned short*)(ws + 25165824);
  unsigned int* keys   = (unsigned int*)(ws + 33554432);
  unsigned short* h    = (unsigned short*)(ws + 16777216);
  int*   nbr   = (int*)(ws + 50331648);
  float* a_src = (float*)(ws + 52428800);
  unsigned short* Whi  = (unsigned short*)(ws + 52428800);
  unsigned short* Wlo  = (unsigned short*)(ws + 52428800 + 131072);
  float* a_dst = (float*)(ws + 52953088);
  float* hsq   = (float*)(ws + 52953088);

  float* out = (float*)d_out;

  k_split <<<BB * (NN / 64), 256, 0, stream>>>(x, xt, xhi, hsq);
  k_wpack <<<HF * CC / 256, 256, 0, stream>>>(W, Whi, Wlo);
  k_screen<<<BB * (NN / 64) * 2, 256, 0, stream>>>(xhi, hsq, cand, keys);
  k_rerank<<<BB * NN / 4, 256, 0, stream>>>(xt, hsq, cand, keys, nbr);
  k_h2    <<<BB * NN / 64, 256, 0, stream>>>(xt, Whi, Wlo, h);
  k_att   <<<BB * NN / 4, 256, 0, stream>>>(h, att_src, att_dst, a_src, a_dst);
  k_out   <<<BB * (NN / 16), 256, 0, stream>>>(h, nbr, a_src, a_dst, bias, out);
}